// Round 3
// baseline (1085.471 us; speedup 1.0000x reference)
//
#include <hip/hip_runtime.h>
#include <math.h>

#define L 2048
#define B 8
#define D 1024
#define ND 16
#define BD (B*D)

__device__ __forceinline__ float sigmoid_precise(float v) {
    return 1.0f / (1.0f + expf(-v));
}
// fast sigmoid: v_exp + v_rcp (~3e-7 rel err; tolerance is 0.0625 abs)
__device__ __forceinline__ float sigmoid_fast(float v) {
    return __builtin_amdgcn_rcpf(1.0f + __expf(-v));
}

// Per-mode decay q[16] for row `row` (row-major params: [2D][ND]).
__device__ __forceinline__ void load_q(const float* __restrict__ damp,
                                       const float* __restrict__ decay,
                                       int row, float* q) {
#pragma unroll
    for (int mg = 0; mg < 4; ++mg) {
        const float4 dp = reinterpret_cast<const float4*>(damp)[row * 4 + mg];
        const float4 dc = reinterpret_cast<const float4*>(decay)[row * 4 + mg];
        q[4*mg+0] = 1.f - sigmoid_fast(dp.x) * sigmoid_fast(dc.x);
        q[4*mg+1] = 1.f - sigmoid_fast(dp.y) * sigmoid_fast(dc.y);
        q[4*mg+2] = 1.f - sigmoid_fast(dp.z) * sigmoid_fast(dc.z);
        q[4*mg+3] = 1.f - sigmoid_fast(dp.w) * sigmoid_fast(dc.w);
    }
}

// Per-mode decay q[16] and output coefficient c[16] (= p * ema * proj / sqrt(ND)).
__device__ __forceinline__ void load_qc(const float* __restrict__ damp,
                                        const float* __restrict__ decay,
                                        const float* __restrict__ ema,
                                        const float* __restrict__ proj,
                                        int row, float* q, float* c) {
#pragma unroll
    for (int mg = 0; mg < 4; ++mg) {
        const float4 dp = reinterpret_cast<const float4*>(damp)[row * 4 + mg];
        const float4 dc = reinterpret_cast<const float4*>(decay)[row * 4 + mg];
        const float4 em = reinterpret_cast<const float4*>(ema)[row * 4 + mg];
        const float4 pj = reinterpret_cast<const float4*>(proj)[row * 4 + mg];
        const float p0 = sigmoid_fast(dp.x), p1 = sigmoid_fast(dp.y),
                    p2 = sigmoid_fast(dp.z), p3 = sigmoid_fast(dp.w);
        q[4*mg+0] = 1.f - p0 * sigmoid_fast(dc.x);
        q[4*mg+1] = 1.f - p1 * sigmoid_fast(dc.y);
        q[4*mg+2] = 1.f - p2 * sigmoid_fast(dc.z);
        q[4*mg+3] = 1.f - p3 * sigmoid_fast(dc.w);
        c[4*mg+0] = p0 * em.x * pj.x * 0.25f;
        c[4*mg+1] = p1 * em.y * pj.y * 0.25f;
        c[4*mg+2] = p2 * em.z * pj.z * 0.25f;
        c[4*mg+3] = p3 * em.w * pj.w * 0.25f;
    }
}

// ---------------- Phase A: per-chunk local states (both directions) ----------
// Block = 128 threads: wave 0 scans forward (u = i), wave 1 backward
// (u = (CK-1)-i = i ^ (CK-1)). One shared code path; rolling 8-deep prefetch.
template<int CK>
__global__ __launch_bounds__(128, 4) void ema_summary_kernel(
    const float* __restrict__ x, const float* __restrict__ damp,
    const float* __restrict__ decay, const int* __restrict__ mask,
    float* __restrict__ fwdS, float* __restrict__ bwdS)
{
    constexpr int NC = L / CK;
    const int lane = threadIdx.x & 63;
    const int wid  = threadIdx.x >> 6;          // 0 = fwd, 1 = bwd
    const int d  = blockIdx.x * 64 + lane;
    const int b  = blockIdx.y;
    const int ch = blockIdx.z;
    const int j0 = ch * CK;
    const int um = wid ? (CK - 1) : 0;          // u = i ^ um

    const float* xp = x + (size_t)j0 * BD + (size_t)b * D + d;
    const int*   mp = mask + (size_t)b * L + j0;       // wave-uniform
    const int row = wid ? (d + D) : d;

    float q[ND], st[ND];
    load_q(damp, decay, row, q);
#pragma unroll
    for (int k = 0; k < ND; ++k) st[k] = 0.f;

#pragma unroll
    for (int g = 0; g < CK; g += 8) {
        float xr[8]; int mr[8];
#pragma unroll
        for (int v = 0; v < 8; ++v) {
            const int u = (g + v) ^ um;
            xr[v] = xp[(size_t)u * BD];
            mr[v] = mp[u];
        }
#pragma unroll
        for (int v = 0; v < 8; ++v) {
            const float xm = xr[v] * (float)mr[v];
#pragma unroll
            for (int k = 0; k < ND; ++k) st[k] = fmaf(q[k], st[k], xm);
        }
    }
    float* Sx = wid ? bwdS : fwdS;
    float4* s4 = reinterpret_cast<float4*>(Sx) + ((size_t)(b * NC + ch) * D + d) * 4;
#pragma unroll
    for (int mg = 0; mg < 4; ++mg)
        s4[mg] = make_float4(st[4*mg+0], st[4*mg+1], st[4*mg+2], st[4*mg+3]);
}

// ---------------- Phase B: prefix across chunks (in-place -> entry states) ---
// One thread per (b, d, mode). All chunk values prefetched, then the two
// serial fma chains (fwd + bwd) interleaved for 2x chain ILP.
template<int CK>
__global__ __launch_bounds__(256) void ema_prefix_kernel(
    const float* __restrict__ damp, const float* __restrict__ decay,
    float* __restrict__ fwdS, float* __restrict__ bwdS)
{
    constexpr int NC = L / CK;
    constexpr int LOG2CK = (CK == 64) ? 6 : 7;
    const int tid = blockIdx.x * 256 + threadIdx.x;
    const int m = tid & (ND - 1);
    const int d = (tid >> 4) & (D - 1);
    const int b = tid >> 14;
    const size_t CS = (size_t)D * ND;   // stride between chunks
    const size_t off = (size_t)b * NC * CS + (size_t)d * ND + m;
    float* fb = fwdS + off;
    float* bb = bwdS + off;

    const int idxf = d * ND + m;
    const int idxb = (d + D) * ND + m;
    float qf = 1.f - sigmoid_fast(damp[idxf]) * sigmoid_fast(decay[idxf]);
    float qb = 1.f - sigmoid_fast(damp[idxb]) * sigmoid_fast(decay[idxb]);
#pragma unroll
    for (int s = 0; s < LOG2CK; ++s) { qf *= qf; qb *= qb; }   // q^CK

    float Ef[NC], Eb[NC];
#pragma unroll
    for (int i = 0; i < NC; ++i) Ef[i] = fb[(size_t)i * CS];
#pragma unroll
    for (int i = 0; i < NC; ++i) Eb[i] = bb[(size_t)i * CS];

    float F = 0.f, G = 0.f;
#pragma unroll
    for (int i = 0; i < NC; ++i) {
        fb[(size_t)i * CS] = F;               F = fmaf(qf, F, Ef[i]);
        bb[(size_t)(NC-1-i) * CS] = G;        G = fmaf(qb, G, Eb[NC-1-i]);
    }
}

// ---------------- Phase C: apply (both directions + residual + silu) ---------
// Block = 128 threads. Wave 0: causal scan (u = i), keeps u<HALF contributions
// (incl. residual) in racc[], writes u>=HALF to its LDS half. Wave 1:
// anti-causal scan (u = i^ (CK-1)), mirrored. One __syncthreads, then each
// wave combines its register half with the other wave's LDS half (mirror
// slot HALF-1-r), applies fast silu, coalesced store.
template<int CK>
__global__ __launch_bounds__(128, 4) void ema_apply_kernel(
    const float* __restrict__ x, const float* __restrict__ damp,
    const float* __restrict__ decay, const float* __restrict__ ema,
    const float* __restrict__ proj, const float* __restrict__ rw,
    const int* __restrict__ mask,
    const float* __restrict__ fwdS, const float* __restrict__ bwdS,
    float* __restrict__ out)
{
    constexpr int NC = L / CK;
    constexpr int HALF = CK / 2;
    __shared__ float hacc[2][HALF][64];      // 16 KB at CK=64

    const int lane = threadIdx.x & 63;
    const int wid  = threadIdx.x >> 6;       // 0 = fwd, 1 = bwd
    const int d  = blockIdx.x * 64 + lane;
    const int b  = blockIdx.y;
    const int ch = blockIdx.z;
    const int j0 = ch * CK;
    const int um = wid ? (CK - 1) : 0;       // u = i ^ um

    const float* xp = x   + (size_t)j0 * BD + (size_t)b * D + d;
    float*       op = out + (size_t)j0 * BD + (size_t)b * D + d;
    const int*   mp = mask + (size_t)b * L + j0;     // wave-uniform
    const int    row  = wid ? (d + D) : d;
    const float  weff = wid ? 0.f : rw[d];           // residual only on fwd wave
    const float* Sx   = wid ? bwdS : fwdS;

    float q[ND], c[ND], st[ND];
    load_qc(damp, decay, ema, proj, row, q, c);
    {
        const float4* s4 = reinterpret_cast<const float4*>(Sx) + ((size_t)(b * NC + ch) * D + d) * 4;
#pragma unroll
        for (int mg = 0; mg < 4; ++mg) {
            const float4 v = s4[mg];
            st[4*mg+0] = v.x; st[4*mg+1] = v.y; st[4*mg+2] = v.z; st[4*mg+3] = v.w;
        }
    }

    float racc[HALF];
#pragma unroll
    for (int g = 0; g < CK; g += 8) {
        float xr[8]; int mr[8];
#pragma unroll
        for (int v = 0; v < 8; ++v) {
            const int u = (g + v) ^ um;
            xr[v] = xp[(size_t)u * BD];
            mr[v] = mp[u];
        }
#pragma unroll
        for (int v = 0; v < 8; ++v) {
            const float xraw = xr[v];
            const float xm   = xraw * (float)mr[v];
#pragma unroll
            for (int k = 0; k < ND; ++k) st[k] = fmaf(q[k], st[k], xm);
            float a0 = c[0] * st[0], a1 = c[1] * st[1],
                  a2 = c[2] * st[2], a3 = c[3] * st[3];
#pragma unroll
            for (int k = 4; k < ND; k += 4) {
                a0 = fmaf(c[k+0], st[k+0], a0);
                a1 = fmaf(c[k+1], st[k+1], a1);
                a2 = fmaf(c[k+2], st[k+2], a2);
                a3 = fmaf(c[k+3], st[k+3], a3);
            }
            const float tv = fmaf(xraw, weff, (a0 + a1) + (a2 + a3));
            const int i = g + v;
            if (i < HALF) racc[i] = tv;
            else          hacc[wid][i - HALF][lane] = tv;
        }
    }
    __syncthreads();

    const int ow = 1 - wid;
#pragma unroll
    for (int r = 0; r < HALF; ++r) {
        const float val = racc[r] + hacc[ow][HALF - 1 - r][lane];
        const int u = r ^ um;
        // fast silu: val * rcp(1 + exp(-val))
        op[(size_t)u * BD] = val * __builtin_amdgcn_rcpf(1.0f + __expf(-val));
    }
}

// ---------------- Fallback: validated single-pass scans ----------------------
template<int DIR>
__device__ __forceinline__ void ema_scan_body(
    const float* __restrict__ x, const float* __restrict__ damp,
    const float* __restrict__ decay, const float* __restrict__ ema,
    const float* __restrict__ proj, const float* __restrict__ rw,
    const int* __restrict__ mask, float* __restrict__ out)
{
    const int t  = threadIdx.x;
    const int ng = t & 3;
    const int dl = t >> 2;
    const int d  = blockIdx.x * 16 + dl;
    const int b  = blockIdx.y;
    const int row = (DIR == 0) ? d : (d + D);

    float q[4], c[4];
#pragma unroll
    for (int k = 0; k < 4; ++k) {
        const int idx = row * ND + ng * 4 + k;
        const float p  = sigmoid_precise(damp[idx]);
        const float sd = sigmoid_precise(decay[idx]);
        q[k] = 1.0f - p * sd;
        c[k] = p * ema[idx] * proj[idx] * 0.25f;
    }
    const float w = rw[d];
    const float* xp = x + (size_t)b * D + d;
    float*       op = out + (size_t)b * D + d;
    const int*   mp = mask + (size_t)b * L;
    float s0 = 0.f, s1 = 0.f, s2 = 0.f, s3 = 0.f;

    for (int jj = 0; jj < L; jj += 4) {
        float xv[4], mf[4];
#pragma unroll
        for (int u = 0; u < 4; ++u) {
            const int j = (DIR == 0) ? (jj + u) : (L - 1 - (jj + u));
            xv[u] = xp[(size_t)j * BD];
            mf[u] = (float)mp[j];
        }
        float acc[4];
#pragma unroll
        for (int u = 0; u < 4; ++u) {
            const float xm = xv[u] * mf[u];
            s0 = fmaf(q[0], s0, xm);
            s1 = fmaf(q[1], s1, xm);
            s2 = fmaf(q[2], s2, xm);
            s3 = fmaf(q[3], s3, xm);
            acc[u] = fmaf(c[1], s1, c[0] * s0) + fmaf(c[3], s3, c[2] * s2);
        }
#pragma unroll
        for (int u = 0; u < 4; ++u) acc[u] += __shfl_xor(acc[u], 1);
#pragma unroll
        for (int u = 0; u < 4; ++u) acc[u] += __shfl_xor(acc[u], 2);
        if (ng == 0) {
#pragma unroll
            for (int u = 0; u < 4; ++u) {
                const int j = (DIR == 0) ? (jj + u) : (L - 1 - (jj + u));
                const size_t oi = (size_t)j * BD;
                if (DIR == 0) op[oi] = fmaf(xv[u], w, acc[u]);
                else { const float v = op[oi] + acc[u]; op[oi] = v / (1.0f + expf(-v)); }
            }
        }
    }
}

__global__ __launch_bounds__(64) void ema_fwd_kernel(
    const float* __restrict__ x, const float* __restrict__ damp,
    const float* __restrict__ decay, const float* __restrict__ ema,
    const float* __restrict__ proj, const float* __restrict__ rw,
    const int* __restrict__ mask, float* __restrict__ out)
{ ema_scan_body<0>(x, damp, decay, ema, proj, rw, mask, out); }

__global__ __launch_bounds__(64) void ema_bwd_kernel(
    const float* __restrict__ x, const float* __restrict__ damp,
    const float* __restrict__ decay, const float* __restrict__ ema,
    const float* __restrict__ proj, const float* __restrict__ rw,
    const int* __restrict__ mask, float* __restrict__ out)
{ ema_scan_body<1>(x, damp, decay, ema, proj, rw, mask, out); }

// ---------------- driver -----------------------------------------------------
template<int CK>
static void launch_chunked(const float* x, const float* damp, const float* decay,
                           const float* ema, const float* proj, const float* rw,
                           const int* mask, float* out, float* ws, hipStream_t stream) {
    constexpr int NC = L / CK;
    float* fwdS = ws;
    float* bwdS = fwdS + (size_t)B * NC * D * ND;
    dim3 g(D / 64, B, NC);
    ema_summary_kernel<CK><<<g, dim3(128), 0, stream>>>(x, damp, decay, mask, fwdS, bwdS);
    ema_prefix_kernel<CK><<<dim3((B * D * ND) / 256), dim3(256), 0, stream>>>(damp, decay, fwdS, bwdS);
    ema_apply_kernel<CK><<<g, dim3(128), 0, stream>>>(x, damp, decay, ema, proj, rw, mask,
                                                      fwdS, bwdS, out);
}

extern "C" void kernel_launch(void* const* d_in, const int* in_sizes, int n_in,
                              void* d_out, int out_size, void* d_ws, size_t ws_size,
                              hipStream_t stream) {
    (void)in_sizes; (void)n_in; (void)out_size;
    const float* x     = (const float*)d_in[0];
    const float* damp  = (const float*)d_in[1];
    const float* decay = (const float*)d_in[2];
    const float* ema   = (const float*)d_in[3];
    const float* proj  = (const float*)d_in[4];
    const float* rw    = (const float*)d_in[5];
    const int*   mask  = (const int*)d_in[6];
    float* out = (float*)d_out;

    const size_t need64 = (size_t)2 * B * (L / 64) * D * ND * sizeof(float);  // 33.6 MB

    if (ws_size >= need64) {
        launch_chunked<64>(x, damp, decay, ema, proj, rw, mask, out, (float*)d_ws, stream);
    } else {
        dim3 grid(D / 16, B);
        dim3 block(64);
        ema_fwd_kernel<<<grid, block, 0, stream>>>(x, damp, decay, ema, proj, rw, mask, out);
        ema_bwd_kernel<<<grid, block, 0, stream>>>(x, damp, decay, ema, proj, rw, mask, out);
    }
}

// Round 4
// 368.231 us; speedup vs baseline: 2.9478x; 2.9478x over previous
//
#include <hip/hip_runtime.h>
#include <math.h>

#define L 2048
#define B 8
#define D 1024
#define ND 16
#define BD (B*D)

__device__ __forceinline__ float sigmoid_precise(float v) {
    return 1.0f / (1.0f + expf(-v));
}
// fast sigmoid: v_exp + v_rcp (~3e-7 rel err; tolerance is 0.0625 abs)
__device__ __forceinline__ float sigmoid_fast(float v) {
    return __builtin_amdgcn_rcpf(1.0f + __expf(-v));
}

// Per-mode decay q[16] for row `row` (row-major params: [2D][ND]).
__device__ __forceinline__ void load_q(const float* __restrict__ damp,
                                       const float* __restrict__ decay,
                                       int row, float* q) {
#pragma unroll
    for (int mg = 0; mg < 4; ++mg) {
        const float4 dp = reinterpret_cast<const float4*>(damp)[row * 4 + mg];
        const float4 dc = reinterpret_cast<const float4*>(decay)[row * 4 + mg];
        q[4*mg+0] = 1.f - sigmoid_fast(dp.x) * sigmoid_fast(dc.x);
        q[4*mg+1] = 1.f - sigmoid_fast(dp.y) * sigmoid_fast(dc.y);
        q[4*mg+2] = 1.f - sigmoid_fast(dp.z) * sigmoid_fast(dc.z);
        q[4*mg+3] = 1.f - sigmoid_fast(dp.w) * sigmoid_fast(dc.w);
    }
}

// Per-mode decay q[16] and output coefficient c[16] (= p * ema * proj / sqrt(ND)).
__device__ __forceinline__ void load_qc(const float* __restrict__ damp,
                                        const float* __restrict__ decay,
                                        const float* __restrict__ ema,
                                        const float* __restrict__ proj,
                                        int row, float* q, float* c) {
#pragma unroll
    for (int mg = 0; mg < 4; ++mg) {
        const float4 dp = reinterpret_cast<const float4*>(damp)[row * 4 + mg];
        const float4 dc = reinterpret_cast<const float4*>(decay)[row * 4 + mg];
        const float4 em = reinterpret_cast<const float4*>(ema)[row * 4 + mg];
        const float4 pj = reinterpret_cast<const float4*>(proj)[row * 4 + mg];
        const float p0 = sigmoid_fast(dp.x), p1 = sigmoid_fast(dp.y),
                    p2 = sigmoid_fast(dp.z), p3 = sigmoid_fast(dp.w);
        q[4*mg+0] = 1.f - p0 * sigmoid_fast(dc.x);
        q[4*mg+1] = 1.f - p1 * sigmoid_fast(dc.y);
        q[4*mg+2] = 1.f - p2 * sigmoid_fast(dc.z);
        q[4*mg+3] = 1.f - p3 * sigmoid_fast(dc.w);
        c[4*mg+0] = p0 * em.x * pj.x * 0.25f;
        c[4*mg+1] = p1 * em.y * pj.y * 0.25f;
        c[4*mg+2] = p2 * em.z * pj.z * 0.25f;
        c[4*mg+3] = p3 * em.w * pj.w * 0.25f;
    }
}

// ---------------- Phase A: per-chunk local states (both directions) ----------
// Block = 128 threads: wave 0 scans forward (u = i), wave 1 backward
// (u = i ^ (CK-1)). One shared code path; rolling 8-deep prefetch. No
// register arrays beyond the 8-deep prefetch -> no scratch.
template<int CK>
__global__ __launch_bounds__(128, 4) void ema_summary_kernel(
    const float* __restrict__ x, const float* __restrict__ damp,
    const float* __restrict__ decay, const int* __restrict__ mask,
    float* __restrict__ fwdS, float* __restrict__ bwdS)
{
    constexpr int NC = L / CK;
    const int lane = threadIdx.x & 63;
    const int wid  = threadIdx.x >> 6;          // 0 = fwd, 1 = bwd
    const int d  = blockIdx.x * 64 + lane;
    const int b  = blockIdx.y;
    const int ch = blockIdx.z;
    const int j0 = ch * CK;
    const int um = wid ? (CK - 1) : 0;          // u = i ^ um

    const float* xp = x + (size_t)j0 * BD + (size_t)b * D + d;
    const int*   mp = mask + (size_t)b * L + j0;       // wave-uniform
    const int row = wid ? (d + D) : d;

    float q[ND], st[ND];
    load_q(damp, decay, row, q);
#pragma unroll
    for (int k = 0; k < ND; ++k) st[k] = 0.f;

#pragma unroll
    for (int g = 0; g < CK; g += 8) {
        float xr[8], mf[8];
#pragma unroll
        for (int v = 0; v < 8; ++v) {
            const int u = (g + v) ^ um;
            xr[v] = xp[(size_t)u * BD];
            mf[v] = (float)mp[u];
        }
#pragma unroll
        for (int v = 0; v < 8; ++v) {
            const float xm = xr[v] * mf[v];
#pragma unroll
            for (int k = 0; k < ND; ++k) st[k] = fmaf(q[k], st[k], xm);
        }
    }
    float* Sx = wid ? bwdS : fwdS;
    float4* s4 = reinterpret_cast<float4*>(Sx) + ((size_t)(b * NC + ch) * D + d) * 4;
#pragma unroll
    for (int mg = 0; mg < 4; ++mg)
        s4[mg] = make_float4(st[4*mg+0], st[4*mg+1], st[4*mg+2], st[4*mg+3]);
}

// ---------------- Phase B: prefix across chunks (in-place -> entry states) ---
// One thread per (b, d, mode). All chunk values prefetched, then the two
// serial fma chains (fwd + bwd) interleaved for 2x chain ILP.
template<int CK>
__global__ __launch_bounds__(256) void ema_prefix_kernel(
    const float* __restrict__ damp, const float* __restrict__ decay,
    float* __restrict__ fwdS, float* __restrict__ bwdS)
{
    constexpr int NC = L / CK;
    constexpr int LOG2CK = (CK == 64) ? 6 : 7;
    const int tid = blockIdx.x * 256 + threadIdx.x;
    const int m = tid & (ND - 1);
    const int d = (tid >> 4) & (D - 1);
    const int b = tid >> 14;
    const size_t CS = (size_t)D * ND;   // stride between chunks
    const size_t off = (size_t)b * NC * CS + (size_t)d * ND + m;
    float* fb = fwdS + off;
    float* bb = bwdS + off;

    const int idxf = d * ND + m;
    const int idxb = (d + D) * ND + m;
    float qf = 1.f - sigmoid_fast(damp[idxf]) * sigmoid_fast(decay[idxf]);
    float qb = 1.f - sigmoid_fast(damp[idxb]) * sigmoid_fast(decay[idxb]);
#pragma unroll
    for (int s = 0; s < LOG2CK; ++s) { qf *= qf; qb *= qb; }   // q^CK

    float Ef[NC], Eb[NC];
#pragma unroll
    for (int i = 0; i < NC; ++i) Ef[i] = fb[(size_t)i * CS];
#pragma unroll
    for (int i = 0; i < NC; ++i) Eb[i] = bb[(size_t)i * CS];

    float F = 0.f, G = 0.f;
#pragma unroll
    for (int i = 0; i < NC; ++i) {
        fb[(size_t)i * CS] = F;               F = fmaf(qf, F, Ef[i]);
        bb[(size_t)(NC-1-i) * CS] = G;        G = fmaf(qb, G, Eb[NC-1-i]);
    }
}

// ---------------- Phase C: apply (both directions + residual + silu) ---------
// Block = 128 threads. Wave 0: causal scan (u = i), wave 1: anti-causal scan
// (u = i ^ (CK-1)). Each wave writes ALL its per-u contributions to its own
// LDS tile (no register arrays -> nothing to spill). One __syncthreads, then
// wave 0 combines+silu+stores u in [0,HALF), wave 1 u in [HALF,CK).
template<int CK>
__global__ __launch_bounds__(128) void ema_apply_kernel(
    const float* __restrict__ x, const float* __restrict__ damp,
    const float* __restrict__ decay, const float* __restrict__ ema,
    const float* __restrict__ proj, const float* __restrict__ rw,
    const int* __restrict__ mask,
    const float* __restrict__ fwdS, const float* __restrict__ bwdS,
    float* __restrict__ out)
{
    constexpr int NC = L / CK;
    constexpr int HALF = CK / 2;
    __shared__ float hacc[2][CK][64];        // 32 KB at CK=64

    const int lane = threadIdx.x & 63;
    const int wid  = threadIdx.x >> 6;       // 0 = fwd, 1 = bwd
    const int d  = blockIdx.x * 64 + lane;
    const int b  = blockIdx.y;
    const int ch = blockIdx.z;
    const int j0 = ch * CK;
    const int um = wid ? (CK - 1) : 0;       // u = i ^ um

    const float* xp = x   + (size_t)j0 * BD + (size_t)b * D + d;
    float*       op = out + (size_t)j0 * BD + (size_t)b * D + d;
    const int*   mp = mask + (size_t)b * L + j0;     // wave-uniform
    const int    row  = wid ? (d + D) : d;
    const float  weff = wid ? 0.f : rw[d];           // residual only on fwd wave
    const float* Sx   = wid ? bwdS : fwdS;

    float q[ND], c[ND], st[ND];
    load_qc(damp, decay, ema, proj, row, q, c);
    {
        const float4* s4 = reinterpret_cast<const float4*>(Sx) + ((size_t)(b * NC + ch) * D + d) * 4;
#pragma unroll
        for (int mg = 0; mg < 4; ++mg) {
            const float4 v = s4[mg];
            st[4*mg+0] = v.x; st[4*mg+1] = v.y; st[4*mg+2] = v.z; st[4*mg+3] = v.w;
        }
    }

#pragma unroll
    for (int g = 0; g < CK; g += 8) {
        float xr[8], mf[8];
#pragma unroll
        for (int v = 0; v < 8; ++v) {
            const int u = (g + v) ^ um;
            xr[v] = xp[(size_t)u * BD];
            mf[v] = (float)mp[u];
        }
#pragma unroll
        for (int v = 0; v < 8; ++v) {
            const int u = (g + v) ^ um;
            const float xraw = xr[v];
            const float xm   = xraw * mf[v];
#pragma unroll
            for (int k = 0; k < ND; ++k) st[k] = fmaf(q[k], st[k], xm);
            float a0 = c[0] * st[0], a1 = c[1] * st[1],
                  a2 = c[2] * st[2], a3 = c[3] * st[3];
#pragma unroll
            for (int k = 4; k < ND; k += 4) {
                a0 = fmaf(c[k+0], st[k+0], a0);
                a1 = fmaf(c[k+1], st[k+1], a1);
                a2 = fmaf(c[k+2], st[k+2], a2);
                a3 = fmaf(c[k+3], st[k+3], a3);
            }
            hacc[wid][u][lane] = fmaf(xraw, weff, (a0 + a1) + (a2 + a3));
        }
    }
    __syncthreads();

    const int ub = wid * HALF;
#pragma unroll
    for (int r = 0; r < HALF; ++r) {
        const int u = ub + r;
        const float val = hacc[0][u][lane] + hacc[1][u][lane];
        // fast silu: val * rcp(1 + exp(-val))
        op[(size_t)u * BD] = val * __builtin_amdgcn_rcpf(1.0f + __expf(-val));
    }
}

// ---------------- Fallback: validated single-pass scans ----------------------
template<int DIR>
__device__ __forceinline__ void ema_scan_body(
    const float* __restrict__ x, const float* __restrict__ damp,
    const float* __restrict__ decay, const float* __restrict__ ema,
    const float* __restrict__ proj, const float* __restrict__ rw,
    const int* __restrict__ mask, float* __restrict__ out)
{
    const int t  = threadIdx.x;
    const int ng = t & 3;
    const int dl = t >> 2;
    const int d  = blockIdx.x * 16 + dl;
    const int b  = blockIdx.y;
    const int row = (DIR == 0) ? d : (d + D);

    float q[4], c[4];
#pragma unroll
    for (int k = 0; k < 4; ++k) {
        const int idx = row * ND + ng * 4 + k;
        const float p  = sigmoid_precise(damp[idx]);
        const float sd = sigmoid_precise(decay[idx]);
        q[k] = 1.0f - p * sd;
        c[k] = p * ema[idx] * proj[idx] * 0.25f;
    }
    const float w = rw[d];
    const float* xp = x + (size_t)b * D + d;
    float*       op = out + (size_t)b * D + d;
    const int*   mp = mask + (size_t)b * L;
    float s0 = 0.f, s1 = 0.f, s2 = 0.f, s3 = 0.f;

    for (int jj = 0; jj < L; jj += 4) {
        float xv[4], mf[4];
#pragma unroll
        for (int u = 0; u < 4; ++u) {
            const int j = (DIR == 0) ? (jj + u) : (L - 1 - (jj + u));
            xv[u] = xp[(size_t)j * BD];
            mf[u] = (float)mp[j];
        }
        float acc[4];
#pragma unroll
        for (int u = 0; u < 4; ++u) {
            const float xm = xv[u] * mf[u];
            s0 = fmaf(q[0], s0, xm);
            s1 = fmaf(q[1], s1, xm);
            s2 = fmaf(q[2], s2, xm);
            s3 = fmaf(q[3], s3, xm);
            acc[u] = fmaf(c[1], s1, c[0] * s0) + fmaf(c[3], s3, c[2] * s2);
        }
#pragma unroll
        for (int u = 0; u < 4; ++u) acc[u] += __shfl_xor(acc[u], 1);
#pragma unroll
        for (int u = 0; u < 4; ++u) acc[u] += __shfl_xor(acc[u], 2);
        if (ng == 0) {
#pragma unroll
            for (int u = 0; u < 4; ++u) {
                const int j = (DIR == 0) ? (jj + u) : (L - 1 - (jj + u));
                const size_t oi = (size_t)j * BD;
                if (DIR == 0) op[oi] = fmaf(xv[u], w, acc[u]);
                else { const float v = op[oi] + acc[u]; op[oi] = v / (1.0f + expf(-v)); }
            }
        }
    }
}

__global__ __launch_bounds__(64) void ema_fwd_kernel(
    const float* __restrict__ x, const float* __restrict__ damp,
    const float* __restrict__ decay, const float* __restrict__ ema,
    const float* __restrict__ proj, const float* __restrict__ rw,
    const int* __restrict__ mask, float* __restrict__ out)
{ ema_scan_body<0>(x, damp, decay, ema, proj, rw, mask, out); }

__global__ __launch_bounds__(64) void ema_bwd_kernel(
    const float* __restrict__ x, const float* __restrict__ damp,
    const float* __restrict__ decay, const float* __restrict__ ema,
    const float* __restrict__ proj, const float* __restrict__ rw,
    const int* __restrict__ mask, float* __restrict__ out)
{ ema_scan_body<1>(x, damp, decay, ema, proj, rw, mask, out); }

// ---------------- driver -----------------------------------------------------
template<int CK>
static void launch_chunked(const float* x, const float* damp, const float* decay,
                           const float* ema, const float* proj, const float* rw,
                           const int* mask, float* out, float* ws, hipStream_t stream) {
    constexpr int NC = L / CK;
    float* fwdS = ws;
    float* bwdS = fwdS + (size_t)B * NC * D * ND;
    dim3 g(D / 64, B, NC);
    ema_summary_kernel<CK><<<g, dim3(128), 0, stream>>>(x, damp, decay, mask, fwdS, bwdS);
    ema_prefix_kernel<CK><<<dim3((B * D * ND) / 256), dim3(256), 0, stream>>>(damp, decay, fwdS, bwdS);
    ema_apply_kernel<CK><<<g, dim3(128), 0, stream>>>(x, damp, decay, ema, proj, rw, mask,
                                                      fwdS, bwdS, out);
}

extern "C" void kernel_launch(void* const* d_in, const int* in_sizes, int n_in,
                              void* d_out, int out_size, void* d_ws, size_t ws_size,
                              hipStream_t stream) {
    (void)in_sizes; (void)n_in; (void)out_size;
    const float* x     = (const float*)d_in[0];
    const float* damp  = (const float*)d_in[1];
    const float* decay = (const float*)d_in[2];
    const float* ema   = (const float*)d_in[3];
    const float* proj  = (const float*)d_in[4];
    const float* rw    = (const float*)d_in[5];
    const int*   mask  = (const int*)d_in[6];
    float* out = (float*)d_out;

    const size_t need64 = (size_t)2 * B * (L / 64) * D * ND * sizeof(float);  // 33.6 MB

    if (ws_size >= need64) {
        launch_chunked<64>(x, damp, decay, ema, proj, rw, mask, out, (float*)d_ws, stream);
    } else {
        dim3 grid(D / 16, B);
        dim3 block(64);
        ema_fwd_kernel<<<grid, block, 0, stream>>>(x, damp, decay, ema, proj, rw, mask, out);
        ema_bwd_kernel<<<grid, block, 0, stream>>>(x, damp, decay, ema, proj, rw, mask, out);
    }
}

// Round 5
// 203.474 us; speedup vs baseline: 5.3347x; 1.8097x over previous
//
#include <hip/hip_runtime.h>
#include <math.h>

#define L 2048
#define B 8
#define D 1024
#define ND 16
#define BD (B*D)

__device__ __forceinline__ float sigmoid_precise(float v) {
    return 1.0f / (1.0f + expf(-v));
}
// fast sigmoid: v_exp + v_rcp (~3e-7 rel err; tolerance is 0.0625 abs)
__device__ __forceinline__ float sigmoid_fast(float v) {
    return __builtin_amdgcn_rcpf(1.0f + __expf(-v));
}

// Per-mode decay q[16] for row `row` (row-major params: [2D][ND]).
__device__ __forceinline__ void load_q(const float* __restrict__ damp,
                                       const float* __restrict__ decay,
                                       int row, float* q) {
#pragma unroll
    for (int mg = 0; mg < 4; ++mg) {
        const float4 dp = reinterpret_cast<const float4*>(damp)[row * 4 + mg];
        const float4 dc = reinterpret_cast<const float4*>(decay)[row * 4 + mg];
        q[4*mg+0] = 1.f - sigmoid_fast(dp.x) * sigmoid_fast(dc.x);
        q[4*mg+1] = 1.f - sigmoid_fast(dp.y) * sigmoid_fast(dc.y);
        q[4*mg+2] = 1.f - sigmoid_fast(dp.z) * sigmoid_fast(dc.z);
        q[4*mg+3] = 1.f - sigmoid_fast(dp.w) * sigmoid_fast(dc.w);
    }
}

// Per-mode decay q[16] and output coefficient c[16] (= p * ema * proj / sqrt(ND)).
__device__ __forceinline__ void load_qc(const float* __restrict__ damp,
                                        const float* __restrict__ decay,
                                        const float* __restrict__ ema,
                                        const float* __restrict__ proj,
                                        int row, float* q, float* c) {
#pragma unroll
    for (int mg = 0; mg < 4; ++mg) {
        const float4 dp = reinterpret_cast<const float4*>(damp)[row * 4 + mg];
        const float4 dc = reinterpret_cast<const float4*>(decay)[row * 4 + mg];
        const float4 em = reinterpret_cast<const float4*>(ema)[row * 4 + mg];
        const float4 pj = reinterpret_cast<const float4*>(proj)[row * 4 + mg];
        const float p0 = sigmoid_fast(dp.x), p1 = sigmoid_fast(dp.y),
                    p2 = sigmoid_fast(dp.z), p3 = sigmoid_fast(dp.w);
        q[4*mg+0] = 1.f - p0 * sigmoid_fast(dc.x);
        q[4*mg+1] = 1.f - p1 * sigmoid_fast(dc.y);
        q[4*mg+2] = 1.f - p2 * sigmoid_fast(dc.z);
        q[4*mg+3] = 1.f - p3 * sigmoid_fast(dc.w);
        c[4*mg+0] = p0 * em.x * pj.x * 0.25f;
        c[4*mg+1] = p1 * em.y * pj.y * 0.25f;
        c[4*mg+2] = p2 * em.z * pj.z * 0.25f;
        c[4*mg+3] = p3 * em.w * pj.w * 0.25f;
    }
}

// ---------------- Phase A: per-chunk local states (both directions) ----------
// Block = 128 threads: wave 0 scans forward (u = i), wave 1 backward
// (u = i ^ (CK-1)). Outer loop is NOT unrolled (bounded liveness: only one
// 16-deep prefetch group in flight -> no scratch spill).
template<int CK>
__global__ __launch_bounds__(128, 2) void ema_summary_kernel(
    const float* __restrict__ x, const float* __restrict__ damp,
    const float* __restrict__ decay, const int* __restrict__ mask,
    float* __restrict__ fwdS, float* __restrict__ bwdS)
{
    constexpr int NC = L / CK;
    const int lane = threadIdx.x & 63;
    const int wid  = threadIdx.x >> 6;          // 0 = fwd, 1 = bwd
    const int d  = blockIdx.x * 64 + lane;
    const int b  = blockIdx.y;
    const int ch = blockIdx.z;
    const int j0 = ch * CK;
    const int um = wid ? (CK - 1) : 0;          // u = i ^ um

    const float* xp = x + (size_t)j0 * BD + (size_t)b * D + d;
    const int*   mp = mask + (size_t)b * L + j0;       // wave-uniform
    const int row = wid ? (d + D) : d;

    float q[ND], st[ND];
    load_q(damp, decay, row, q);
#pragma unroll
    for (int k = 0; k < ND; ++k) st[k] = 0.f;

#pragma unroll 1
    for (int g = 0; g < CK; g += 16) {
        float xr[16], mf[16];
#pragma unroll
        for (int v = 0; v < 16; ++v) {
            const int u = (g + v) ^ um;
            xr[v] = xp[(size_t)u * BD];
            mf[v] = (float)mp[u];
        }
#pragma unroll
        for (int v = 0; v < 16; ++v) {
            const float xm = xr[v] * mf[v];
#pragma unroll
            for (int k = 0; k < ND; ++k) st[k] = fmaf(q[k], st[k], xm);
        }
    }
    float* Sx = wid ? bwdS : fwdS;
    float4* s4 = reinterpret_cast<float4*>(Sx) + ((size_t)(b * NC + ch) * D + d) * 4;
#pragma unroll
    for (int mg = 0; mg < 4; ++mg)
        s4[mg] = make_float4(st[4*mg+0], st[4*mg+1], st[4*mg+2], st[4*mg+3]);
}

// ---------------- Phase B: prefix across chunks (in-place -> entry states) ---
// One thread per (b, d, mode). All chunk values prefetched, then the two
// serial fma chains (fwd + bwd) interleaved for 2x chain ILP.
template<int CK>
__global__ __launch_bounds__(256) void ema_prefix_kernel(
    const float* __restrict__ damp, const float* __restrict__ decay,
    float* __restrict__ fwdS, float* __restrict__ bwdS)
{
    constexpr int NC = L / CK;
    constexpr int LOG2CK = (CK == 64) ? 6 : 7;
    const int tid = blockIdx.x * 256 + threadIdx.x;
    const int m = tid & (ND - 1);
    const int d = (tid >> 4) & (D - 1);
    const int b = tid >> 14;
    const size_t CS = (size_t)D * ND;   // stride between chunks
    const size_t off = (size_t)b * NC * CS + (size_t)d * ND + m;
    float* fb = fwdS + off;
    float* bb = bwdS + off;

    const int idxf = d * ND + m;
    const int idxb = (d + D) * ND + m;
    float qf = 1.f - sigmoid_fast(damp[idxf]) * sigmoid_fast(decay[idxf]);
    float qb = 1.f - sigmoid_fast(damp[idxb]) * sigmoid_fast(decay[idxb]);
#pragma unroll
    for (int s = 0; s < LOG2CK; ++s) { qf *= qf; qb *= qb; }   // q^CK

    float Ef[NC], Eb[NC];
#pragma unroll
    for (int i = 0; i < NC; ++i) Ef[i] = fb[(size_t)i * CS];
#pragma unroll
    for (int i = 0; i < NC; ++i) Eb[i] = bb[(size_t)i * CS];

    float F = 0.f, G = 0.f;
#pragma unroll
    for (int i = 0; i < NC; ++i) {
        fb[(size_t)i * CS] = F;               F = fmaf(qf, F, Ef[i]);
        bb[(size_t)(NC-1-i) * CS] = G;        G = fmaf(qb, G, Eb[NC-1-i]);
    }
}

// ---------------- Phase C: apply (both directions + residual + silu) ---------
// Block = 128 threads. Wave 0: causal scan (u = i), wave 1: anti-causal scan
// (u = i ^ (CK-1)). Each wave writes ALL its per-u contributions to its own
// LDS tile (no register arrays -> nothing to spill; outer loop not unrolled
// -> bounded liveness). One __syncthreads, then wave 0 combines+silu+stores
// u in [0,HALF), wave 1 u in [HALF,CK).
template<int CK>
__global__ __launch_bounds__(128, 2) void ema_apply_kernel(
    const float* __restrict__ x, const float* __restrict__ damp,
    const float* __restrict__ decay, const float* __restrict__ ema,
    const float* __restrict__ proj, const float* __restrict__ rw,
    const int* __restrict__ mask,
    const float* __restrict__ fwdS, const float* __restrict__ bwdS,
    float* __restrict__ out)
{
    constexpr int NC = L / CK;
    constexpr int HALF = CK / 2;
    __shared__ float hacc[2][CK][64];        // 32 KB at CK=64

    const int lane = threadIdx.x & 63;
    const int wid  = threadIdx.x >> 6;       // 0 = fwd, 1 = bwd
    const int d  = blockIdx.x * 64 + lane;
    const int b  = blockIdx.y;
    const int ch = blockIdx.z;
    const int j0 = ch * CK;
    const int um = wid ? (CK - 1) : 0;       // u = i ^ um

    const float* xp = x   + (size_t)j0 * BD + (size_t)b * D + d;
    float*       op = out + (size_t)j0 * BD + (size_t)b * D + d;
    const int*   mp = mask + (size_t)b * L + j0;     // wave-uniform
    const int    row  = wid ? (d + D) : d;
    const float  weff = wid ? 0.f : rw[d];           // residual only on fwd wave
    const float* Sx   = wid ? bwdS : fwdS;

    float q[ND], c[ND], st[ND];
    load_qc(damp, decay, ema, proj, row, q, c);
    {
        const float4* s4 = reinterpret_cast<const float4*>(Sx) + ((size_t)(b * NC + ch) * D + d) * 4;
#pragma unroll
        for (int mg = 0; mg < 4; ++mg) {
            const float4 v = s4[mg];
            st[4*mg+0] = v.x; st[4*mg+1] = v.y; st[4*mg+2] = v.z; st[4*mg+3] = v.w;
        }
    }

#pragma unroll 1
    for (int g = 0; g < CK; g += 8) {
        float xr[8], mf[8];
#pragma unroll
        for (int v = 0; v < 8; ++v) {
            const int u = (g + v) ^ um;
            xr[v] = xp[(size_t)u * BD];
            mf[v] = (float)mp[u];
        }
#pragma unroll
        for (int v = 0; v < 8; ++v) {
            const int u = (g + v) ^ um;
            const float xraw = xr[v];
            const float xm   = xraw * mf[v];
#pragma unroll
            for (int k = 0; k < ND; ++k) st[k] = fmaf(q[k], st[k], xm);
            float a0 = c[0] * st[0], a1 = c[1] * st[1],
                  a2 = c[2] * st[2], a3 = c[3] * st[3];
#pragma unroll
            for (int k = 4; k < ND; k += 4) {
                a0 = fmaf(c[k+0], st[k+0], a0);
                a1 = fmaf(c[k+1], st[k+1], a1);
                a2 = fmaf(c[k+2], st[k+2], a2);
                a3 = fmaf(c[k+3], st[k+3], a3);
            }
            hacc[wid][u][lane] = fmaf(xraw, weff, (a0 + a1) + (a2 + a3));
        }
    }
    __syncthreads();

    const int ub = wid * HALF;
#pragma unroll 1
    for (int r = 0; r < HALF; ++r) {
        const int u = ub + r;
        const float val = hacc[0][u][lane] + hacc[1][u][lane];
        // fast silu: val * rcp(1 + exp(-val))
        op[(size_t)u * BD] = val * __builtin_amdgcn_rcpf(1.0f + __expf(-val));
    }
}

// ---------------- Fallback: validated single-pass scans ----------------------
template<int DIR>
__device__ __forceinline__ void ema_scan_body(
    const float* __restrict__ x, const float* __restrict__ damp,
    const float* __restrict__ decay, const float* __restrict__ ema,
    const float* __restrict__ proj, const float* __restrict__ rw,
    const int* __restrict__ mask, float* __restrict__ out)
{
    const int t  = threadIdx.x;
    const int ng = t & 3;
    const int dl = t >> 2;
    const int d  = blockIdx.x * 16 + dl;
    const int b  = blockIdx.y;
    const int row = (DIR == 0) ? d : (d + D);

    float q[4], c[4];
#pragma unroll
    for (int k = 0; k < 4; ++k) {
        const int idx = row * ND + ng * 4 + k;
        const float p  = sigmoid_precise(damp[idx]);
        const float sd = sigmoid_precise(decay[idx]);
        q[k] = 1.0f - p * sd;
        c[k] = p * ema[idx] * proj[idx] * 0.25f;
    }
    const float w = rw[d];
    const float* xp = x + (size_t)b * D + d;
    float*       op = out + (size_t)b * D + d;
    const int*   mp = mask + (size_t)b * L;
    float s0 = 0.f, s1 = 0.f, s2 = 0.f, s3 = 0.f;

    for (int jj = 0; jj < L; jj += 4) {
        float xv[4], mf[4];
#pragma unroll
        for (int u = 0; u < 4; ++u) {
            const int j = (DIR == 0) ? (jj + u) : (L - 1 - (jj + u));
            xv[u] = xp[(size_t)j * BD];
            mf[u] = (float)mp[j];
        }
        float acc[4];
#pragma unroll
        for (int u = 0; u < 4; ++u) {
            const float xm = xv[u] * mf[u];
            s0 = fmaf(q[0], s0, xm);
            s1 = fmaf(q[1], s1, xm);
            s2 = fmaf(q[2], s2, xm);
            s3 = fmaf(q[3], s3, xm);
            acc[u] = fmaf(c[1], s1, c[0] * s0) + fmaf(c[3], s3, c[2] * s2);
        }
#pragma unroll
        for (int u = 0; u < 4; ++u) acc[u] += __shfl_xor(acc[u], 1);
#pragma unroll
        for (int u = 0; u < 4; ++u) acc[u] += __shfl_xor(acc[u], 2);
        if (ng == 0) {
#pragma unroll
            for (int u = 0; u < 4; ++u) {
                const int j = (DIR == 0) ? (jj + u) : (L - 1 - (jj + u));
                const size_t oi = (size_t)j * BD;
                if (DIR == 0) op[oi] = fmaf(xv[u], w, acc[u]);
                else { const float v = op[oi] + acc[u]; op[oi] = v / (1.0f + expf(-v)); }
            }
        }
    }
}

__global__ __launch_bounds__(64) void ema_fwd_kernel(
    const float* __restrict__ x, const float* __restrict__ damp,
    const float* __restrict__ decay, const float* __restrict__ ema,
    const float* __restrict__ proj, const float* __restrict__ rw,
    const int* __restrict__ mask, float* __restrict__ out)
{ ema_scan_body<0>(x, damp, decay, ema, proj, rw, mask, out); }

__global__ __launch_bounds__(64) void ema_bwd_kernel(
    const float* __restrict__ x, const float* __restrict__ damp,
    const float* __restrict__ decay, const float* __restrict__ ema,
    const float* __restrict__ proj, const float* __restrict__ rw,
    const int* __restrict__ mask, float* __restrict__ out)
{ ema_scan_body<1>(x, damp, decay, ema, proj, rw, mask, out); }

// ---------------- driver -----------------------------------------------------
template<int CK>
static void launch_chunked(const float* x, const float* damp, const float* decay,
                           const float* ema, const float* proj, const float* rw,
                           const int* mask, float* out, float* ws, hipStream_t stream) {
    constexpr int NC = L / CK;
    float* fwdS = ws;
    float* bwdS = fwdS + (size_t)B * NC * D * ND;
    dim3 g(D / 64, B, NC);
    ema_summary_kernel<CK><<<g, dim3(128), 0, stream>>>(x, damp, decay, mask, fwdS, bwdS);
    ema_prefix_kernel<CK><<<dim3((B * D * ND) / 256), dim3(256), 0, stream>>>(damp, decay, fwdS, bwdS);
    ema_apply_kernel<CK><<<g, dim3(128), 0, stream>>>(x, damp, decay, ema, proj, rw, mask,
                                                      fwdS, bwdS, out);
}

extern "C" void kernel_launch(void* const* d_in, const int* in_sizes, int n_in,
                              void* d_out, int out_size, void* d_ws, size_t ws_size,
                              hipStream_t stream) {
    (void)in_sizes; (void)n_in; (void)out_size;
    const float* x     = (const float*)d_in[0];
    const float* damp  = (const float*)d_in[1];
    const float* decay = (const float*)d_in[2];
    const float* ema   = (const float*)d_in[3];
    const float* proj  = (const float*)d_in[4];
    const float* rw    = (const float*)d_in[5];
    const int*   mask  = (const int*)d_in[6];
    float* out = (float*)d_out;

    const size_t need64 = (size_t)2 * B * (L / 64) * D * ND * sizeof(float);  // 33.6 MB

    if (ws_size >= need64) {
        launch_chunked<64>(x, damp, decay, ema, proj, rw, mask, out, (float*)d_ws, stream);
    } else {
        dim3 grid(D / 16, B);
        dim3 block(64);
        ema_fwd_kernel<<<grid, block, 0, stream>>>(x, damp, decay, ema, proj, rw, mask, out);
        ema_bwd_kernel<<<grid, block, 0, stream>>>(x, damp, decay, ema, proj, rw, mask, out);
    }
}

// Round 6
// 194.195 us; speedup vs baseline: 5.5896x; 1.0478x over previous
//
#include <hip/hip_runtime.h>
#include <math.h>

#define L 2048
#define B 8
#define D 1024
#define ND 16
#define BD (B*D)

__device__ __forceinline__ float sigmoid_precise(float v) {
    return 1.0f / (1.0f + expf(-v));
}
// fast sigmoid: v_exp + v_rcp (~3e-7 rel err; tolerance is 0.0625 abs)
__device__ __forceinline__ float sigmoid_fast(float v) {
    return __builtin_amdgcn_rcpf(1.0f + __expf(-v));
}

// Per-mode decay q[16] for row `row` (row-major params: [2D][ND]).
__device__ __forceinline__ void load_q(const float* __restrict__ damp,
                                       const float* __restrict__ decay,
                                       int row, float* q) {
#pragma unroll
    for (int mg = 0; mg < 4; ++mg) {
        const float4 dp = reinterpret_cast<const float4*>(damp)[row * 4 + mg];
        const float4 dc = reinterpret_cast<const float4*>(decay)[row * 4 + mg];
        q[4*mg+0] = 1.f - sigmoid_fast(dp.x) * sigmoid_fast(dc.x);
        q[4*mg+1] = 1.f - sigmoid_fast(dp.y) * sigmoid_fast(dc.y);
        q[4*mg+2] = 1.f - sigmoid_fast(dp.z) * sigmoid_fast(dc.z);
        q[4*mg+3] = 1.f - sigmoid_fast(dp.w) * sigmoid_fast(dc.w);
    }
}

// Per-mode decay q[16] and output coefficient c[16] (= p * ema * proj / sqrt(ND)).
__device__ __forceinline__ void load_qc(const float* __restrict__ damp,
                                        const float* __restrict__ decay,
                                        const float* __restrict__ ema,
                                        const float* __restrict__ proj,
                                        int row, float* q, float* c) {
#pragma unroll
    for (int mg = 0; mg < 4; ++mg) {
        const float4 dp = reinterpret_cast<const float4*>(damp)[row * 4 + mg];
        const float4 dc = reinterpret_cast<const float4*>(decay)[row * 4 + mg];
        const float4 em = reinterpret_cast<const float4*>(ema)[row * 4 + mg];
        const float4 pj = reinterpret_cast<const float4*>(proj)[row * 4 + mg];
        const float p0 = sigmoid_fast(dp.x), p1 = sigmoid_fast(dp.y),
                    p2 = sigmoid_fast(dp.z), p3 = sigmoid_fast(dp.w);
        q[4*mg+0] = 1.f - p0 * sigmoid_fast(dc.x);
        q[4*mg+1] = 1.f - p1 * sigmoid_fast(dc.y);
        q[4*mg+2] = 1.f - p2 * sigmoid_fast(dc.z);
        q[4*mg+3] = 1.f - p3 * sigmoid_fast(dc.w);
        c[4*mg+0] = p0 * em.x * pj.x * 0.25f;
        c[4*mg+1] = p1 * em.y * pj.y * 0.25f;
        c[4*mg+2] = p2 * em.z * pj.z * 0.25f;
        c[4*mg+3] = p3 * em.w * pj.w * 0.25f;
    }
}

// ---------------- Phase A: per-chunk local states (both directions) ----------
// Block = 128 threads: wave 0 scans forward (u = i), wave 1 backward
// (u = i ^ (CK-1)). Outer loop is NOT unrolled (bounded liveness: only one
// 16-deep prefetch group in flight -> no scratch spill).
template<int CK>
__global__ __launch_bounds__(128, 2) void ema_summary_kernel(
    const float* __restrict__ x, const float* __restrict__ damp,
    const float* __restrict__ decay, const int* __restrict__ mask,
    float* __restrict__ fwdS, float* __restrict__ bwdS)
{
    constexpr int NC = L / CK;
    const int lane = threadIdx.x & 63;
    const int wid  = threadIdx.x >> 6;          // 0 = fwd, 1 = bwd
    const int d  = blockIdx.x * 64 + lane;
    const int b  = blockIdx.y;
    const int ch = blockIdx.z;
    const int j0 = ch * CK;
    const int um = wid ? (CK - 1) : 0;          // u = i ^ um

    const float* xp = x + (size_t)j0 * BD + (size_t)b * D + d;
    const int*   mp = mask + (size_t)b * L + j0;       // wave-uniform
    const int row = wid ? (d + D) : d;

    float q[ND], st[ND];
    load_q(damp, decay, row, q);
#pragma unroll
    for (int k = 0; k < ND; ++k) st[k] = 0.f;

#pragma unroll 1
    for (int g = 0; g < CK; g += 16) {
        float xr[16], mf[16];
#pragma unroll
        for (int v = 0; v < 16; ++v) {
            const int u = (g + v) ^ um;
            xr[v] = xp[(size_t)u * BD];
            mf[v] = (float)mp[u];
        }
#pragma unroll
        for (int v = 0; v < 16; ++v) {
            const float xm = xr[v] * mf[v];
#pragma unroll
            for (int k = 0; k < ND; ++k) st[k] = fmaf(q[k], st[k], xm);
        }
    }
    float* Sx = wid ? bwdS : fwdS;
    float4* s4 = reinterpret_cast<float4*>(Sx) + ((size_t)(b * NC + ch) * D + d) * 4;
#pragma unroll
    for (int mg = 0; mg < 4; ++mg)
        s4[mg] = make_float4(st[4*mg+0], st[4*mg+1], st[4*mg+2], st[4*mg+3]);
}

// ---------------- Phase B: prefix across chunks (in-place -> entry states) ---
// One thread per (b, d, mode). All chunk values prefetched, then the two
// serial fma chains (fwd + bwd) interleaved for 2x chain ILP.
template<int CK>
__global__ __launch_bounds__(256) void ema_prefix_kernel(
    const float* __restrict__ damp, const float* __restrict__ decay,
    float* __restrict__ fwdS, float* __restrict__ bwdS)
{
    constexpr int NC = L / CK;
    constexpr int LOG2CK = (CK == 64) ? 6 : 7;
    const int tid = blockIdx.x * 256 + threadIdx.x;
    const int m = tid & (ND - 1);
    const int d = (tid >> 4) & (D - 1);
    const int b = tid >> 14;
    const size_t CS = (size_t)D * ND;   // stride between chunks
    const size_t off = (size_t)b * NC * CS + (size_t)d * ND + m;
    float* fb = fwdS + off;
    float* bb = bwdS + off;

    const int idxf = d * ND + m;
    const int idxb = (d + D) * ND + m;
    float qf = 1.f - sigmoid_fast(damp[idxf]) * sigmoid_fast(decay[idxf]);
    float qb = 1.f - sigmoid_fast(damp[idxb]) * sigmoid_fast(decay[idxb]);
#pragma unroll
    for (int s = 0; s < LOG2CK; ++s) { qf *= qf; qb *= qb; }   // q^CK

    float Ef[NC], Eb[NC];
#pragma unroll
    for (int i = 0; i < NC; ++i) Ef[i] = fb[(size_t)i * CS];
#pragma unroll
    for (int i = 0; i < NC; ++i) Eb[i] = bb[(size_t)i * CS];

    float F = 0.f, G = 0.f;
#pragma unroll
    for (int i = 0; i < NC; ++i) {
        fb[(size_t)i * CS] = F;               F = fmaf(qf, F, Ef[i]);
        bb[(size_t)(NC-1-i) * CS] = G;        G = fmaf(qb, G, Eb[NC-1-i]);
    }
}

// ---------------- Phase C: apply (both directions + residual + silu) ---------
// Block = 128 threads; wave 0 = causal scan (u ascending), wave 1 =
// anti-causal (u descending). KEY: only the FIRST half of each wave's scan
// goes through LDS (16 KB, not 32):
//   phase 1 (i<HALF): wave 0 computes u=0..31 -> hacc[0][u]; wave 1 computes
//                     u=63..32 -> hacc[1][u&31]. __syncthreads().
//   phase 2 (i>=HALF): each wave continues its scan, combines with the OTHER
//                     wave's LDS slot hacc[1-wid][u&31], silu, direct store.
// No register arrays (nothing to spill), outer loops not unrolled.
template<int CK>
__global__ __launch_bounds__(128, 2) void ema_apply_kernel(
    const float* __restrict__ x, const float* __restrict__ damp,
    const float* __restrict__ decay, const float* __restrict__ ema,
    const float* __restrict__ proj, const float* __restrict__ rw,
    const int* __restrict__ mask,
    const float* __restrict__ fwdS, const float* __restrict__ bwdS,
    float* __restrict__ out)
{
    constexpr int NC = L / CK;
    constexpr int HALF = CK / 2;
    __shared__ float hacc[2][HALF][64];      // 16 KB at CK=64

    const int lane = threadIdx.x & 63;
    const int wid  = threadIdx.x >> 6;       // 0 = fwd, 1 = bwd
    const int d  = blockIdx.x * 64 + lane;
    const int b  = blockIdx.y;
    const int ch = blockIdx.z;
    const int j0 = ch * CK;
    const int um = wid ? (CK - 1) : 0;       // u = i ^ um

    const float* xp = x   + (size_t)j0 * BD + (size_t)b * D + d;
    float*       op = out + (size_t)j0 * BD + (size_t)b * D + d;
    const int*   mp = mask + (size_t)b * L + j0;     // wave-uniform
    const int    row  = wid ? (d + D) : d;
    const float  weff = wid ? 0.f : rw[d];           // residual only on fwd wave
    const float* Sx   = wid ? bwdS : fwdS;

    float q[ND], c[ND], st[ND];
    load_qc(damp, decay, ema, proj, row, q, c);
    {
        const float4* s4 = reinterpret_cast<const float4*>(Sx) + ((size_t)(b * NC + ch) * D + d) * 4;
#pragma unroll
        for (int mg = 0; mg < 4; ++mg) {
            const float4 v = s4[mg];
            st[4*mg+0] = v.x; st[4*mg+1] = v.y; st[4*mg+2] = v.z; st[4*mg+3] = v.w;
        }
    }

    // ---- phase 1: first half of this wave's scan -> LDS ----
#pragma unroll 1
    for (int g = 0; g < HALF; g += 8) {
        float xr[8], mf[8];
#pragma unroll
        for (int v = 0; v < 8; ++v) {
            const int u = (g + v) ^ um;
            xr[v] = xp[(size_t)u * BD];
            mf[v] = (float)mp[u];
        }
#pragma unroll
        for (int v = 0; v < 8; ++v) {
            const int u = (g + v) ^ um;
            const float xraw = xr[v];
            const float xm   = xraw * mf[v];
#pragma unroll
            for (int k = 0; k < ND; ++k) st[k] = fmaf(q[k], st[k], xm);
            float a0 = c[0] * st[0], a1 = c[1] * st[1],
                  a2 = c[2] * st[2], a3 = c[3] * st[3];
#pragma unroll
            for (int k = 4; k < ND; k += 4) {
                a0 = fmaf(c[k+0], st[k+0], a0);
                a1 = fmaf(c[k+1], st[k+1], a1);
                a2 = fmaf(c[k+2], st[k+2], a2);
                a3 = fmaf(c[k+3], st[k+3], a3);
            }
            hacc[wid][u & (HALF - 1)][lane] = fmaf(xraw, weff, (a0 + a1) + (a2 + a3));
        }
    }
    __syncthreads();

    // ---- phase 2: second half of scan + combine with other wave's LDS half ----
    const int ow = 1 - wid;
#pragma unroll 1
    for (int g = HALF; g < CK; g += 8) {
        float xr[8], mf[8];
#pragma unroll
        for (int v = 0; v < 8; ++v) {
            const int u = (g + v) ^ um;
            xr[v] = xp[(size_t)u * BD];
            mf[v] = (float)mp[u];
        }
#pragma unroll
        for (int v = 0; v < 8; ++v) {
            const int u = (g + v) ^ um;
            const float xraw = xr[v];
            const float xm   = xraw * mf[v];
#pragma unroll
            for (int k = 0; k < ND; ++k) st[k] = fmaf(q[k], st[k], xm);
            float a0 = c[0] * st[0], a1 = c[1] * st[1],
                  a2 = c[2] * st[2], a3 = c[3] * st[3];
#pragma unroll
            for (int k = 4; k < ND; k += 4) {
                a0 = fmaf(c[k+0], st[k+0], a0);
                a1 = fmaf(c[k+1], st[k+1], a1);
                a2 = fmaf(c[k+2], st[k+2], a2);
                a3 = fmaf(c[k+3], st[k+3], a3);
            }
            const float tv  = fmaf(xraw, weff, (a0 + a1) + (a2 + a3));
            const float val = tv + hacc[ow][u & (HALF - 1)][lane];
            // fast silu: val * rcp(1 + exp(-val))
            op[(size_t)u * BD] = val * __builtin_amdgcn_rcpf(1.0f + __expf(-val));
        }
    }
}

// ---------------- Fallback: validated single-pass scans ----------------------
template<int DIR>
__device__ __forceinline__ void ema_scan_body(
    const float* __restrict__ x, const float* __restrict__ damp,
    const float* __restrict__ decay, const float* __restrict__ ema,
    const float* __restrict__ proj, const float* __restrict__ rw,
    const int* __restrict__ mask, float* __restrict__ out)
{
    const int t  = threadIdx.x;
    const int ng = t & 3;
    const int dl = t >> 2;
    const int d  = blockIdx.x * 16 + dl;
    const int b  = blockIdx.y;
    const int row = (DIR == 0) ? d : (d + D);

    float q[4], c[4];
#pragma unroll
    for (int k = 0; k < 4; ++k) {
        const int idx = row * ND + ng * 4 + k;
        const float p  = sigmoid_precise(damp[idx]);
        const float sd = sigmoid_precise(decay[idx]);
        q[k] = 1.0f - p * sd;
        c[k] = p * ema[idx] * proj[idx] * 0.25f;
    }
    const float w = rw[d];
    const float* xp = x + (size_t)b * D + d;
    float*       op = out + (size_t)b * D + d;
    const int*   mp = mask + (size_t)b * L;
    float s0 = 0.f, s1 = 0.f, s2 = 0.f, s3 = 0.f;

    for (int jj = 0; jj < L; jj += 4) {
        float xv[4], mf[4];
#pragma unroll
        for (int u = 0; u < 4; ++u) {
            const int j = (DIR == 0) ? (jj + u) : (L - 1 - (jj + u));
            xv[u] = xp[(size_t)j * BD];
            mf[u] = (float)mp[j];
        }
        float acc[4];
#pragma unroll
        for (int u = 0; u < 4; ++u) {
            const float xm = xv[u] * mf[u];
            s0 = fmaf(q[0], s0, xm);
            s1 = fmaf(q[1], s1, xm);
            s2 = fmaf(q[2], s2, xm);
            s3 = fmaf(q[3], s3, xm);
            acc[u] = fmaf(c[1], s1, c[0] * s0) + fmaf(c[3], s3, c[2] * s2);
        }
#pragma unroll
        for (int u = 0; u < 4; ++u) acc[u] += __shfl_xor(acc[u], 1);
#pragma unroll
        for (int u = 0; u < 4; ++u) acc[u] += __shfl_xor(acc[u], 2);
        if (ng == 0) {
#pragma unroll
            for (int u = 0; u < 4; ++u) {
                const int j = (DIR == 0) ? (jj + u) : (L - 1 - (jj + u));
                const size_t oi = (size_t)j * BD;
                if (DIR == 0) op[oi] = fmaf(xv[u], w, acc[u]);
                else { const float v = op[oi] + acc[u]; op[oi] = v / (1.0f + expf(-v)); }
            }
        }
    }
}

__global__ __launch_bounds__(64) void ema_fwd_kernel(
    const float* __restrict__ x, const float* __restrict__ damp,
    const float* __restrict__ decay, const float* __restrict__ ema,
    const float* __restrict__ proj, const float* __restrict__ rw,
    const int* __restrict__ mask, float* __restrict__ out)
{ ema_scan_body<0>(x, damp, decay, ema, proj, rw, mask, out); }

__global__ __launch_bounds__(64) void ema_bwd_kernel(
    const float* __restrict__ x, const float* __restrict__ damp,
    const float* __restrict__ decay, const float* __restrict__ ema,
    const float* __restrict__ proj, const float* __restrict__ rw,
    const int* __restrict__ mask, float* __restrict__ out)
{ ema_scan_body<1>(x, damp, decay, ema, proj, rw, mask, out); }

// ---------------- driver -----------------------------------------------------
template<int CK>
static void launch_chunked(const float* x, const float* damp, const float* decay,
                           const float* ema, const float* proj, const float* rw,
                           const int* mask, float* out, float* ws, hipStream_t stream) {
    constexpr int NC = L / CK;
    float* fwdS = ws;
    float* bwdS = fwdS + (size_t)B * NC * D * ND;
    dim3 g(D / 64, B, NC);
    ema_summary_kernel<CK><<<g, dim3(128), 0, stream>>>(x, damp, decay, mask, fwdS, bwdS);
    ema_prefix_kernel<CK><<<dim3((B * D * ND) / 256), dim3(256), 0, stream>>>(damp, decay, fwdS, bwdS);
    ema_apply_kernel<CK><<<g, dim3(128), 0, stream>>>(x, damp, decay, ema, proj, rw, mask,
                                                      fwdS, bwdS, out);
}

extern "C" void kernel_launch(void* const* d_in, const int* in_sizes, int n_in,
                              void* d_out, int out_size, void* d_ws, size_t ws_size,
                              hipStream_t stream) {
    (void)in_sizes; (void)n_in; (void)out_size;
    const float* x     = (const float*)d_in[0];
    const float* damp  = (const float*)d_in[1];
    const float* decay = (const float*)d_in[2];
    const float* ema   = (const float*)d_in[3];
    const float* proj  = (const float*)d_in[4];
    const float* rw    = (const float*)d_in[5];
    const int*   mask  = (const int*)d_in[6];
    float* out = (float*)d_out;

    const size_t need64 = (size_t)2 * B * (L / 64) * D * ND * sizeof(float);  // 33.6 MB

    if (ws_size >= need64) {
        launch_chunked<64>(x, damp, decay, ema, proj, rw, mask, out, (float*)d_ws, stream);
    } else {
        dim3 grid(D / 16, B);
        dim3 block(64);
        ema_fwd_kernel<<<grid, block, 0, stream>>>(x, damp, decay, ema, proj, rw, mask, out);
        ema_bwd_kernel<<<grid, block, 0, stream>>>(x, damp, decay, ema, proj, rw, mask, out);
    }
}